// Round 6
// baseline (243.308 us; speedup 1.0000x reference)
//
#include <hip/hip_runtime.h>
#include <hip/hip_bf16.h>

#define NEG_SLOPE 0.2f
#define BN_EPS 1e-5f
#define BSHIFT 7          // 128 nodes per bucket; src packed in low 25 bits (N < 2^25)
#define P_PART 256        // scatter partitions
#define MAXB 512          // max buckets supported (N <= 65536)

typedef unsigned int uint32;
typedef unsigned short ushort16;
typedef __attribute__((ext_vector_type(8))) short bf16x8;
typedef __attribute__((ext_vector_type(4))) float f32x4;
typedef __attribute__((ext_vector_type(2))) float f32x2;

__device__ __forceinline__ ushort16 f2bf(float f) {
    uint32 u = __float_as_uint(f);
    u = (u + 0x7fff + ((u >> 16) & 1)) >> 16;  // round-to-nearest-even
    return (ushort16)u;
}

// packed FMA: acc.{x,y} += ex * {lo(u), hi(u)} (bf16 pair widened to f32)
__device__ __forceinline__ f32x2 pkfma(f32x2 ex2, uint32 u, f32x2 acc) {
    f32x2 f;
    f.x = __uint_as_float(u << 16);
    f.y = __uint_as_float(u & 0xffff0000u);
    asm("v_pk_fma_f32 %0, %1, %2, %0" : "+v"(acc) : "v"(ex2), "v"(f));
    return acc;
}

// ---- shared helper: per-block exclusive scan of rowtot -> sb[0..nbuck] (sb[nbuck]=Etot) ----
__device__ __forceinline__ void scan_bbase(const int* __restrict__ rowtot, int nbuck,
                                           int Etot, int* sb /* MAXB+1 ints */) {
    const int t = threadIdx.x;
    int v0 = (t < nbuck) ? rowtot[t] : 0;
    int v1 = (256 + t < nbuck) ? rowtot[256 + t] : 0;
    sb[t] = v0;
    sb[256 + t] = v1;
    __syncthreads();
    for (int off = 1; off < 512; off <<= 1) {
        int a0 = (t >= off) ? sb[t - off] : 0;
        int a1 = (256 + t >= off) ? sb[256 + t - off] : 0;
        __syncthreads();
        sb[t] += a0;
        sb[256 + t] += a1;
        __syncthreads();
    }
    int i0 = sb[t], i1 = sb[256 + t];
    __syncthreads();
    sb[t] = i0 - v0;              // exclusive
    sb[256 + t] = i1 - v1;        // indices >= nbuck naturally hold Etot (pad v=0)
    if (t == 0) sb[MAXB] = Etot;  // only needed when nbuck == MAXB
    __syncthreads();
}

// ---- pack one extended-W column (device body; fused into prep kernel) ----
template <int OC, int C>
__device__ __forceinline__ void pack_col(int col, int k, const float* __restrict__ W,
                                         const float* __restrict__ a_s,
                                         const float* __restrict__ a_d,
                                         ushort16* __restrict__ wt) {
    float v = 0.f;
    if (col < OC) {
        v = W[k * OC + col];
    } else if (col < OC + 2) {
        int hh = col - OC;
        float s = 0.f;
        for (int c = 0; c < C; ++c) s += W[k * OC + hh * C + c] * a_s[hh * C + c];
        v = s;
    } else if (col < OC + 4) {
        int hh = col - OC - 2;
        float s = 0.f;
        for (int c = 0; c < C; ++c) s += W[k * OC + hh * C + c] * a_d[hh * C + c];
        v = s;
    }
    wt[(size_t)col * 128 + k] = f2bf(v);
}

// ==================== MFMA GEMM body: h = x @ Wext (K=128) ====================
template <int OC, int NT, bool AF32>
__device__ __forceinline__ void gemm_body(int gb, const void* __restrict__ xin,
                                          const ushort16* __restrict__ wt,
                                          ushort16* __restrict__ h, float4* __restrict__ att,
                                          float2* __restrict__ asc, int N) {
    const int wave = threadIdx.x >> 6, lane = threadIdx.x & 63;
    const int tile = gb * 4 + wave;
    if (tile * 16 >= N) return;
    const int m = lane & 15, quad = lane >> 4;
    const int node = tile * 16 + m;

    bf16x8 a[4];
    if (AF32) {
        const float* xr = (const float*)xin + (size_t)node * 128 + quad * 8;
#pragma unroll
        for (int c = 0; c < 4; ++c) {
            float4 u = *(const float4*)(xr + c * 32);
            float4 v = *(const float4*)(xr + c * 32 + 4);
            bf16x8 t;
            t[0] = (short)f2bf(u.x); t[1] = (short)f2bf(u.y);
            t[2] = (short)f2bf(u.z); t[3] = (short)f2bf(u.w);
            t[4] = (short)f2bf(v.x); t[5] = (short)f2bf(v.y);
            t[6] = (short)f2bf(v.z); t[7] = (short)f2bf(v.w);
            a[c] = t;
        }
    } else {
        const ushort16* xr = (const ushort16*)xin + (size_t)node * 128 + quad * 8;
#pragma unroll
        for (int c = 0; c < 4; ++c) a[c] = *(const bf16x8*)(xr + c * 32);
    }

    for (int t = 0; t < NT; ++t) {
        const ushort16* wr = wt + ((size_t)(t * 16 + m)) * 128 + quad * 8;
        bf16x8 b[4];
#pragma unroll
        for (int c = 0; c < 4; ++c) b[c] = *(const bf16x8*)(wr + c * 32);
        f32x4 acc = {0.f, 0.f, 0.f, 0.f};
#pragma unroll
        for (int c = 0; c < 4; ++c)
            acc = __builtin_amdgcn_mfma_f32_16x16x32_bf16(a[c], b[c], acc, 0, 0, 0);
        if (t * 16 < OC) {
#pragma unroll
            for (int r = 0; r < 4; ++r) {
                int nrow = tile * 16 + quad * 4 + r;
                h[(size_t)nrow * OC + t * 16 + m] = f2bf(acc[r]);
            }
        } else if (m < 4) {
#pragma unroll
            for (int r = 0; r < 4; ++r) {
                int nrow = tile * 16 + quad * 4 + r;
                ((float*)(att + nrow))[m] = acc[r];
                if (m < 2) ((float*)(asc + nrow))[m] = acc[r];
            }
        }
    }
}

// == K1: fused prep (hist | pack W1 | pack W2 | BN fold | graphsum zero | graph bounds) ==
__global__ __launch_bounds__(256) void fused_prep(
    const int* __restrict__ ei, int E, int Etot, int nbuck, int chunk, int* __restrict__ hist,
    const float* __restrict__ W1, const float* __restrict__ as1, const float* __restrict__ ad1,
    ushort16* __restrict__ wt1,
    const float* __restrict__ W2, const float* __restrict__ as2, const float* __restrict__ ad2,
    ushort16* __restrict__ wt2,
    const float* __restrict__ b1, const float* __restrict__ g1, const float* __restrict__ be1,
    const float* __restrict__ mu1, const float* __restrict__ vr1,
    const float* __restrict__ b2, const float* __restrict__ g2, const float* __restrict__ be2,
    const float* __restrict__ mu2, const float* __restrict__ vr2,
    float2* __restrict__ bn1, float2* __restrict__ bn2, float* __restrict__ graphsum,
    const int* __restrict__ batch, int N, int G, int* __restrict__ gstart) {
    const int bid = blockIdx.x;
    if (bid < P_PART) {
        // ---- role: per-partition bucket histogram ----
        __shared__ int lh[MAXB];
        const int p = bid;
        for (int i = threadIdx.x; i < nbuck; i += 256) lh[i] = 0;
        __syncthreads();
        const int beg = p * chunk;
        const int end = min(beg + chunk, Etot);
        for (int i = beg + threadIdx.x; i < end; i += 256) {
            int d = (i < E) ? ei[E + i] : i - E;
            atomicAdd(&lh[d >> BSHIFT], 1);
        }
        __syncthreads();
        for (int i = threadIdx.x; i < nbuck; i += 256) hist[(size_t)i * P_PART + p] = lh[i];
        return;
    }
    int rb = bid - P_PART;
    if (rb < 72) {
        // ---- role: pack W1 (144 cols, 2 per block) ----
        pack_col<128, 64>(rb * 2 + (threadIdx.x >> 7), threadIdx.x & 127, W1, as1, ad1, wt1);
        return;
    }
    rb -= 72;
    if (rb < 40) {
        // ---- role: pack W2 (80 cols, 2 per block) ----
        pack_col<64, 32>(rb * 2 + (threadIdx.x >> 7), threadIdx.x & 127, W2, as2, ad2, wt2);
        return;
    }
    rb -= 40;
    if (rb == 0) {
        // ---- role: fold BN params into per-channel (A, C): out = A*val + C ----
        const int c = threadIdx.x;
        if (c < 128) {
            float A = g1[c] * rsqrtf(vr1[c] + BN_EPS);
            bn1[c] = make_float2(A, A * (b1[c] - mu1[c]) + be1[c]);
        } else if (c < 160) {
            const int c2 = c - 128;
            float A = g2[c2] * rsqrtf(vr2[c2] + BN_EPS);
            bn2[c2] = make_float2(A, A * (b2[c2] - mu2[c2]) + be2[c2]);
        }
        return;
    }
    rb -= 1;
    const int zb = (G * 32 + 255) >> 8;
    if (rb < zb) {
        // ---- role: zero graphsum (gather2 accumulates into it atomically) ----
        int idx = rb * 256 + (int)threadIdx.x;
        if (idx < G * 32) graphsum[idx] = 0.f;
        return;
    }
    rb -= zb;
    {
        // ---- role: graph bounds (binary search; batch sorted) ----
        int g = rb * 256 + (int)threadIdx.x;
        if (g > G) return;
        if (g == G) { gstart[G] = N; return; }
        int lo = 0, hi = N;
        while (lo < hi) { int mid = (lo + hi) >> 1; if (batch[mid] < g) lo = mid + 1; else hi = mid; }
        gstart[g] = lo;
    }
}

// ---- K2: per-bucket exclusive scan over its 256 partition counts (block per bucket) ----
__global__ __launch_bounds__(P_PART) void row_scan(int* __restrict__ hist,
                                                   int* __restrict__ rowtot) {
    const int b = blockIdx.x;
    __shared__ int s[P_PART];
    const int t = threadIdx.x;
    int v = hist[(size_t)b * P_PART + t];
    s[t] = v;
    __syncthreads();
    for (int off = 1; off < P_PART; off <<= 1) {
        int u = (t >= off) ? s[t - off] : 0;
        __syncthreads();
        s[t] += u;
        __syncthreads();
    }
    hist[(size_t)b * P_PART + t] = s[t] - v;  // exclusive within bucket
    if (t == P_PART - 1) rowtot[b] = s[t];
}

// ====== K3: fused (rank_scatter | gemm1) — gemm1 has no dependency on the CSR chain ======
__global__ __launch_bounds__(256) void fused_scatter_gemm1(
    const int* __restrict__ ei, int E, int Etot, int nbuck, int chunk,
    const int* __restrict__ hist, const int* __restrict__ rowtot, uint32* __restrict__ ebuf,
    const void* __restrict__ x, const ushort16* __restrict__ wt1,
    ushort16* __restrict__ h1, float4* __restrict__ att1, float2* __restrict__ asc1, int N) {
    const int bid = blockIdx.x;
    if (bid < P_PART) {
        // ---- role: rank scatter (LDS cursors over disjoint (b,p) ranges) ----
        __shared__ int sb[MAXB + 1];
        __shared__ int cur[MAXB];
        scan_bbase(rowtot, nbuck, Etot, sb);
        const int p = bid;
        for (int i = threadIdx.x; i < nbuck; i += 256)
            cur[i] = sb[i] + hist[(size_t)i * P_PART + p];
        __syncthreads();
        const int beg = p * chunk;
        const int end = min(beg + chunk, Etot);
        for (int i = beg + threadIdx.x; i < end; i += 256) {
            int s_, d_;
            if (i < E) { s_ = ei[i]; d_ = ei[E + i]; }
            else       { s_ = d_ = i - E; }
            int pos = atomicAdd(&cur[d_ >> BSHIFT], 1);
            ebuf[pos] = ((uint32)(d_ & ((1 << BSHIFT) - 1)) << 25) | (uint32)s_;
        }
    } else {
        // ---- role: layer-1 GEMM ----
        gemm_body<128, 9, true>(bid - P_PART, x, wt1, h1, att1, asc1, N);
    }
}

// ---- K4: block per bucket — node-degree histogram + scan -> base[], place edges ----
__global__ __launch_bounds__(256) void bucket_place(
    const int* __restrict__ rowtot, int nbuck, int Etot, const uint32* __restrict__ ebuf,
    int N, int* __restrict__ base, int* __restrict__ csr_src) {
    const int bk = blockIdx.x;
    __shared__ int sb[MAXB + 1];
    __shared__ int ldeg[1 << BSHIFT];
    __shared__ int sscan[1 << BSHIFT];
    __shared__ int lcur[1 << BSHIFT];
    scan_bbase(rowtot, nbuck, Etot, sb);
    const int t = threadIdx.x;
    if (t < (1 << BSHIFT)) { ldeg[t] = 0; lcur[t] = 0; }
    __syncthreads();
    const int beg = sb[bk], end = sb[bk + 1];
    for (int i = beg + t; i < end; i += 256) atomicAdd(&ldeg[ebuf[i] >> 25], 1);
    __syncthreads();
    if (t < 128) sscan[t] = ldeg[t];
    __syncthreads();
    for (int off = 1; off < 128; off <<= 1) {
        int v = 0;
        if (t < 128 && t >= off) v = sscan[t - off];
        __syncthreads();
        if (t < 128) sscan[t] += v;
        __syncthreads();
    }
    if (t < 128) {
        int node = (bk << BSHIFT) + t;
        if (node < N) base[node] = beg + sscan[t] - ldeg[t];
    }
    __syncthreads();
    for (int i = beg + t; i < end; i += 256) {
        uint32 pk = ebuf[i];
        int dl = (int)(pk >> 25);
        int s_ = (int)(pk & 0x1FFFFFFu);
        int pos = beg + (sscan[dl] - ldeg[dl]) + atomicAdd(&lcur[dl], 1);
        csr_src[pos] = s_;
    }
}

// ========== K5: layer-1 gather + BN + ReLU + FUSED layer-2 GEMM ==========
// Gather phase identical to R5 (latency-pipelined). Epilogue writes the block's
// 16x128 bf16 tile to LDS (row stride 272B -> <=2-way bank aliasing) instead of
// global; after one barrier the 4 waves run the 16x80 MFMA against wt2 and emit
// h2/att2/asc2 directly. Removes the gemm2 kernel AND agg1b's 2x12.8MB round trip.
__global__ __launch_bounds__(256) void gat_gather1(
    const int* __restrict__ base, const int* __restrict__ csr_src, int Etot, int N,
    const ushort16* __restrict__ h, const float4* __restrict__ att,
    const float2* __restrict__ asc, const float2* __restrict__ bn1,
    const ushort16* __restrict__ wt2, ushort16* __restrict__ h2,
    float4* __restrict__ att2, float2* __restrict__ asc2) {
    __shared__ char agg_lds[16 * 272];
    const int tid = threadIdx.x;
    const int nr = tid >> 4;                    // node row in tile (0..15)
    const int node = blockIdx.x * 16 + nr;
    const bool live = node < N;
    const int t = tid & 63;        // lane in wave
    const int q = tid & 15;        // lane in group: channels 8q..8q+7
    const int gbase = t & 48;      // group's first lane (within wave)
    const int hh = q >> 3;         // head
    const int hbit = q & 8;        // head bit for ex-shuffle lane
    const int eh = q & 7;          // edge slot this lane evaluates in phase 1
    int beg = 0, deg = 0;
    float ad = 0.f;
    if (live) {
        beg = base[node];
        const int end = (node + 1 < N) ? base[node + 1] : Etot;
        deg = end - beg;           // >= 1 (self loop)
        const float4 adn = att[node];
        ad = hh ? adn.w : adn.z;
    }
    const char* hq = (const char*)h + q * 16;   // this lane's 16B slice of each row

    f32x2 ac0 = {0.f, 0.f}, ac1 = {0.f, 0.f}, ac2 = {0.f, 0.f}, ac3 = {0.f, 0.f};
    float ssum = 0.f;

    // prefetch chunk 0's source index (clamped to slot 0 for invalid lanes)
    int sidxme = csr_src[beg + ((eh < deg) ? eh : 0)];

    for (int c0e = 0; c0e < deg; c0e += 8) {
        const int degc = min(deg - c0e, 8);
        const bool ok = eh < degc;
        const int offme = sidxme << 8;          // 256B rows
        const float av = ((const float*)asc)[2 * sidxme + hh];
        uint4 hv[8];
#pragma unroll
        for (int s = 0; s < 8; ++s) {
            const int ofs = __shfl(offme, gbase + s, 64);
            hv[s] = *(const uint4*)(hq + ofs);
        }
        const int nb = c0e + 8;
        const int na = (nb < deg) ? (nb + ((eh < deg - nb) ? eh : 0)) : 0;
        const int sidx_next = csr_src[beg + na];
        float e = av + ad;
        e = e > 0.f ? e : NEG_SLOPE * e;
        const float x = ok ? __expf(e) : 0.f;
        float r = x;
#pragma unroll
        for (int off = 1; off < 8; off <<= 1) r += __shfl_xor(r, off, 64);
        ssum += r;
#pragma unroll
        for (int e0 = 0; e0 < 8; e0 += 4) {
            if (e0 < degc) {
#pragma unroll
                for (int j = 0; j < 4; ++j) {
                    const float ex = __shfl(x, (gbase + e0 + j) | hbit, 64);
                    f32x2 ex2; ex2.x = ex; ex2.y = ex;
                    ac0 = pkfma(ex2, hv[e0 + j].x, ac0);
                    ac1 = pkfma(ex2, hv[e0 + j].y, ac1);
                    ac2 = pkfma(ex2, hv[e0 + j].z, ac2);
                    ac3 = pkfma(ex2, hv[e0 + j].w, ac3);
                }
            }
        }
        sidxme = sidx_next;
    }
    // ---- epilogue: folded BN + ReLU -> LDS tile (bf16) ----
    const float inv = 1.f / (ssum + 1e-16f);
    const int c0 = 8 * q;
    const float4* bp = (const float4*)(bn1 + c0);  // (A,C) pairs, channels c0..c0+7
    const float4 w0 = bp[0], w1 = bp[1], w2 = bp[2], w3 = bp[3];
    float va[8] = {ac0.x, ac0.y, ac1.x, ac1.y, ac2.x, ac2.y, ac3.x, ac3.y};
    float Ac[8] = {w0.x, w0.z, w1.x, w1.z, w2.x, w2.z, w3.x, w3.z};
    float Cc[8] = {w0.y, w0.w, w1.y, w1.w, w2.y, w2.w, w3.y, w3.w};
    uint32 pk[4];
#pragma unroll
    for (int i = 0; i < 8; i += 2) {
        float v0 = fmaxf(fmaf(Ac[i], va[i] * inv, Cc[i]), 0.f);
        float v1 = fmaxf(fmaf(Ac[i + 1], va[i + 1] * inv, Cc[i + 1]), 0.f);
        pk[i >> 1] = (uint32)f2bf(v0) | ((uint32)f2bf(v1) << 16);
    }
    *(uint4*)(agg_lds + nr * 272 + q * 16) = make_uint4(pk[0], pk[1], pk[2], pk[3]);
    __syncthreads();

    // ---- fused layer-2 GEMM: 16x128 (LDS) x 128x80 (wt2) ----
    const int wave = tid >> 6;
    const int m = t & 15, quad = t >> 4;
    bf16x8 a[4];
#pragma unroll
    for (int c = 0; c < 4; ++c)
        a[c] = *(const bf16x8*)(agg_lds + m * 272 + quad * 16 + c * 64);
    const int tile0 = blockIdx.x * 16;
#pragma unroll
    for (int tt = 0; tt < 2; ++tt) {
        const int tcol = wave + tt * 4;          // wave0: tiles 0,4; waves1-3: tiles 1-3
        if (tcol < 5) {
            const ushort16* wr = wt2 + ((size_t)(tcol * 16 + m)) * 128 + quad * 8;
            bf16x8 b[4];
#pragma unroll
            for (int c = 0; c < 4; ++c) b[c] = *(const bf16x8*)(wr + c * 32);
            f32x4 acc = {0.f, 0.f, 0.f, 0.f};
#pragma unroll
            for (int c = 0; c < 4; ++c)
                acc = __builtin_amdgcn_mfma_f32_16x16x32_bf16(a[c], b[c], acc, 0, 0, 0);
            if (tcol * 16 < 64) {
#pragma unroll
                for (int r = 0; r < 4; ++r) {
                    int nrow = tile0 + quad * 4 + r;
                    if (nrow < N) h2[(size_t)nrow * 64 + tcol * 16 + m] = f2bf(acc[r]);
                }
            } else if (m < 4) {
#pragma unroll
                for (int r = 0; r < 4; ++r) {
                    int nrow = tile0 + quad * 4 + r;
                    if (nrow < N) {
                        ((float*)(att2 + nrow))[m] = acc[r];
                        if (m < 2) ((float*)(asc2 + nrow))[m] = acc[r];
                    }
                }
            }
        }
    }
}

// ====== K6: layer-2 gather + head-mean + folded BN + atomic graph-pool ======
__global__ __launch_bounds__(256) void gat_gather2(
    const int* __restrict__ base, const int* __restrict__ csr_src, int Etot, int N,
    const ushort16* __restrict__ h2, const float4* __restrict__ att,
    const float2* __restrict__ asc, const float2* __restrict__ bn2,
    const int* __restrict__ batch, float* __restrict__ graphsum) {
    const int tid = threadIdx.x;
    const int node = blockIdx.x * 16 + (tid >> 4);
    if (node >= N) return;
    const int t = tid & 63;
    const int q = tid & 15;        // channels 4q..4q+3
    const int gbase = t & 48;
    const int hh = q >> 3;
    const int hbit = q & 8;
    const int eh = q & 7;
    const int gid = batch[node];   // issued early; latency hides under gather
    const int beg = base[node];
    const int end = (node + 1 < N) ? base[node + 1] : Etot;
    const int deg = end - beg;
    const float4 adn = att[node];
    const float ad = hh ? adn.w : adn.z;
    const char* hq = (const char*)h2 + q * 8;   // this lane's 8B slice of each row

    f32x2 ac0 = {0.f, 0.f}, ac1 = {0.f, 0.f};
    float ssum = 0.f;

    int sidxme = csr_src[beg + ((eh < deg) ? eh : 0)];

    for (int c0e = 0; c0e < deg; c0e += 8) {
        const int degc = min(deg - c0e, 8);
        const bool ok = eh < degc;
        const int offme = sidxme << 7;          // 128B rows
        const float av = ((const float*)asc)[2 * sidxme + hh];
        uint2 hv[8];
#pragma unroll
        for (int s = 0; s < 8; ++s) {
            const int ofs = __shfl(offme, gbase + s, 64);
            hv[s] = *(const uint2*)(hq + ofs);
        }
        const int nb = c0e + 8;
        const int na = (nb < deg) ? (nb + ((eh < deg - nb) ? eh : 0)) : 0;
        const int sidx_next = csr_src[beg + na];
        float e = av + ad;
        e = e > 0.f ? e : NEG_SLOPE * e;
        const float x = ok ? __expf(e) : 0.f;
        float r = x;
#pragma unroll
        for (int off = 1; off < 8; off <<= 1) r += __shfl_xor(r, off, 64);
        ssum += r;
#pragma unroll
        for (int e0 = 0; e0 < 8; e0 += 4) {
            if (e0 < degc) {
#pragma unroll
                for (int j = 0; j < 4; ++j) {
                    const float ex = __shfl(x, (gbase + e0 + j) | hbit, 64);
                    f32x2 ex2; ex2.x = ex; ex2.y = ex;
                    ac0 = pkfma(ex2, hv[e0 + j].x, ac0);
                    ac1 = pkfma(ex2, hv[e0 + j].y, ac1);
                }
            }
        }
        sidxme = sidx_next;
    }
    const float inv = 1.f / (ssum + 1e-16f);
    float v0 = ac0.x * inv, v1 = ac0.y * inv, v2 = ac1.x * inv, v3 = ac1.y * inv;
    // head mean: lane q<8 (head0 ch 4q..4q+3) pairs with lane q+8 (head1 ch 32+4q..)
    const int psrc = gbase | ((q + 8) & 15);
    float p0 = __shfl(v0, psrc, 64);
    float p1 = __shfl(v1, psrc, 64);
    float p2 = __shfl(v2, psrc, 64);
    float p3 = __shfl(v3, psrc, 64);
    if (q < 8) {
        const int c0 = 4 * q;
        const float4* bp = (const float4*)(bn2 + c0);  // (A,C) pairs, channels c0..c0+3
        const float4 w0 = bp[0], w1 = bp[1];
        float m0 = fmaf(w0.x, 0.5f * (v0 + p0), w0.y);
        float m1 = fmaf(w0.z, 0.5f * (v1 + p1), w0.w);
        float m2 = fmaf(w1.x, 0.5f * (v2 + p2), w1.y);
        float m3 = fmaf(w1.z, 0.5f * (v3 + p3), w1.w);
        float* gs = graphsum + (size_t)gid * 32 + c0;
        atomicAdd(gs + 0, m0);
        atomicAdd(gs + 1, m1);
        atomicAdd(gs + 2, m2);
        atomicAdd(gs + 3, m3);
    }
}

// ============ K7: per-graph mean + log_softmax over 32 classes (tiny) ============
__global__ __launch_bounds__(64) void pool_finish(
    const float* __restrict__ graphsum, const int* __restrict__ gstart,
    float* __restrict__ out) {
    const int g = blockIdx.x;
    if (threadIdx.x >= 32) return;
    const int c = threadIdx.x;
    const int n0 = gstart[g], n1 = gstart[g + 1];
    float v = graphsum[(size_t)g * 32 + c] / fmaxf((float)(n1 - n0), 1.f);
    float m = v;
#pragma unroll
    for (int off = 16; off >= 1; off >>= 1) m = fmaxf(m, __shfl_xor(m, off, 32));
    float ex = __expf(v - m);
    float s = ex;
#pragma unroll
    for (int off = 16; off >= 1; off >>= 1) s += __shfl_xor(s, off, 32);
    out[g * 32 + c] = v - m - logf(s);
}

extern "C" void kernel_launch(void* const* d_in, const int* in_sizes, int n_in,
                              void* d_out, int out_size, void* d_ws, size_t ws_size,
                              hipStream_t stream) {
    const float* x   = (const float*)d_in[0];
    const int* ei    = (const int*)d_in[1];
    const int* batch = (const int*)d_in[2];
    const float* W1  = (const float*)d_in[3];
    const float* as1 = (const float*)d_in[4];
    const float* ad1 = (const float*)d_in[5];
    const float* b1  = (const float*)d_in[6];
    const float* g1  = (const float*)d_in[7];
    const float* be1 = (const float*)d_in[8];
    const float* mu1 = (const float*)d_in[9];
    const float* vr1 = (const float*)d_in[10];
    const float* W2  = (const float*)d_in[11];
    const float* as2 = (const float*)d_in[12];
    const float* ad2 = (const float*)d_in[13];
    const float* b2  = (const float*)d_in[14];
    const float* g2  = (const float*)d_in[15];
    const float* be2 = (const float*)d_in[16];
    const float* mu2 = (const float*)d_in[17];
    const float* vr2 = (const float*)d_in[18];
    float* out = (float*)d_out;

    const int N = in_sizes[0] / 128;
    const int E = in_sizes[1] / 2;
    const int Etot = E + N;
    const int G = out_size / 32;
    const int nbuck = (N + (1 << BSHIFT) - 1) >> BSHIFT;
    const int chunk = (Etot + P_PART - 1) / P_PART;
    const int M = nbuck * P_PART;
    const int ntile = (N + 15) / 16;
    const int gemm_grid = (ntile + 3) / 4;
    const int gbb = (G + 1 + 255) / 256;      // graph_bounds blocks (g in [0, G])
    const int zb = (G * 32 + 255) / 256;      // graphsum zero blocks

    // ---- workspace layout (units: floats; keep every region 16B-aligned) ----
    float* p = (float*)d_ws;
    size_t o = 0;
    auto al = [&]() { o = (o + 3) & ~(size_t)3; };
    ushort16* h1b   = (ushort16*)(p + o); o += (size_t)N * 64;  al();  // N*128 bf16
    ushort16* h2b   = (ushort16*)(p + o); o += (size_t)N * 32;  al();  // N*64 bf16
    float4* att1 = (float4*)(p + o); o += (size_t)N * 4;  al();
    float4* att2 = (float4*)(p + o); o += (size_t)N * 4;  al();
    float2* asc1 = (float2*)(p + o); o += (size_t)N * 2;  al();
    float2* asc2 = (float2*)(p + o); o += (size_t)N * 2;  al();
    ushort16* wt1 = (ushort16*)(p + o); o += (size_t)144 * 64; al();   // 144x128 bf16
    ushort16* wt2 = (ushort16*)(p + o); o += (size_t)80 * 64;  al();   // 80x128 bf16
    float2* bn1  = (float2*)(p + o); o += (size_t)128 * 2; al();
    float2* bn2  = (float2*)(p + o); o += (size_t)32 * 2;  al();
    float* graphsum = p + o; o += (size_t)G * 32; al();
    int* csr_src = (int*)(p + o); o += (size_t)Etot; al();
    uint32* ebuf = (uint32*)(p + o); o += (size_t)Etot; al();
    int* base    = (int*)(p + o); o += (size_t)N;    al();
    int* hist    = (int*)(p + o); o += (size_t)M;    al();
    int* rowtot  = (int*)(p + o); o += (size_t)nbuck + 4; al();
    int* gstart  = (int*)(p + o); o += (size_t)G + 4; al();
    // (graphsum is zeroed by fused_prep; everything else fully written before read)

    // K1: hist | pack W1 | pack W2 | BN fold | graphsum zero | graph bounds
    fused_prep<<<P_PART + 72 + 40 + 1 + zb + gbb, 256, 0, stream>>>(
        ei, E, Etot, nbuck, chunk, hist, W1, as1, ad1, wt1, W2, as2, ad2, wt2,
        b1, g1, be1, mu1, vr1, b2, g2, be2, mu2, vr2, bn1, bn2, graphsum,
        batch, N, G, gstart);
    // K2: per-bucket scan of partition counts
    row_scan<<<nbuck, P_PART, 0, stream>>>(hist, rowtot);
    // K3: rank scatter | layer-1 GEMM (independent; overlap in one launch)
    fused_scatter_gemm1<<<P_PART + gemm_grid, 256, 0, stream>>>(
        ei, E, Etot, nbuck, chunk, hist, rowtot, ebuf, x, wt1, h1b, att1, asc1, N);
    // K4: per-bucket placement -> CSR
    bucket_place<<<nbuck, 256, 0, stream>>>(rowtot, nbuck, Etot, ebuf, N, base, csr_src);
    // K5: layer-1 gather + BN + ReLU + fused layer-2 GEMM (16 nodes per block)
    gat_gather1<<<ntile, 256, 0, stream>>>(base, csr_src, Etot, N, h1b, att1, asc1,
                                           bn1, wt2, h2b, att2, asc2);
    // K6: layer-2 gather + head-mean + BN + atomic graph pool
    gat_gather2<<<ntile, 256, 0, stream>>>(base, csr_src, Etot, N, h2b, att2, asc2,
                                           bn2, batch, graphsum);
    // K7: per-graph mean + log_softmax
    pool_finish<<<G, 64, 0, stream>>>(graphsum, gstart, out);
}

// Round 7
// 206.606 us; speedup vs baseline: 1.1776x; 1.1776x over previous
//
#include <hip/hip_runtime.h>
#include <hip/hip_bf16.h>

#define NEG_SLOPE 0.2f
#define BN_EPS 1e-5f
#define BSHIFT 7          // 128 nodes per bucket; src packed in low 25 bits (N < 2^25)
#define P_PART 256        // scatter partitions
#define MAXB 512          // max buckets supported (N <= 65536)

typedef unsigned int uint32;
typedef unsigned short ushort16;
typedef __attribute__((ext_vector_type(8))) short bf16x8;
typedef __attribute__((ext_vector_type(4))) float f32x4;
typedef __attribute__((ext_vector_type(2))) float f32x2;

__device__ __forceinline__ ushort16 f2bf(float f) {
    uint32 u = __float_as_uint(f);
    u = (u + 0x7fff + ((u >> 16) & 1)) >> 16;  // round-to-nearest-even
    return (ushort16)u;
}

// packed FMA: acc.{x,y} += ex * {lo(u), hi(u)} (bf16 pair widened to f32)
__device__ __forceinline__ f32x2 pkfma(f32x2 ex2, uint32 u, f32x2 acc) {
    f32x2 f;
    f.x = __uint_as_float(u << 16);
    f.y = __uint_as_float(u & 0xffff0000u);
    asm("v_pk_fma_f32 %0, %1, %2, %0" : "+v"(acc) : "v"(ex2), "v"(f));
    return acc;
}

// ---- shared helper: per-block exclusive scan of rowtot -> sb[0..nbuck] (sb[nbuck]=Etot) ----
__device__ __forceinline__ void scan_bbase(const int* __restrict__ rowtot, int nbuck,
                                           int Etot, int* sb /* MAXB+1 ints */) {
    const int t = threadIdx.x;
    int v0 = (t < nbuck) ? rowtot[t] : 0;
    int v1 = (256 + t < nbuck) ? rowtot[256 + t] : 0;
    sb[t] = v0;
    sb[256 + t] = v1;
    __syncthreads();
    for (int off = 1; off < 512; off <<= 1) {
        int a0 = (t >= off) ? sb[t - off] : 0;
        int a1 = (256 + t >= off) ? sb[256 + t - off] : 0;
        __syncthreads();
        sb[t] += a0;
        sb[256 + t] += a1;
        __syncthreads();
    }
    int i0 = sb[t], i1 = sb[256 + t];
    __syncthreads();
    sb[t] = i0 - v0;              // exclusive
    sb[256 + t] = i1 - v1;        // indices >= nbuck naturally hold Etot (pad v=0)
    if (t == 0) sb[MAXB] = Etot;  // only needed when nbuck == MAXB
    __syncthreads();
}

// ---- pack one extended-W column (device body; fused into prep kernel) ----
template <int OC, int C>
__device__ __forceinline__ void pack_col(int col, int k, const float* __restrict__ W,
                                         const float* __restrict__ a_s,
                                         const float* __restrict__ a_d,
                                         ushort16* __restrict__ wt) {
    float v = 0.f;
    if (col < OC) {
        v = W[k * OC + col];
    } else if (col < OC + 2) {
        int hh = col - OC;
        float s = 0.f;
        for (int c = 0; c < C; ++c) s += W[k * OC + hh * C + c] * a_s[hh * C + c];
        v = s;
    } else if (col < OC + 4) {
        int hh = col - OC - 2;
        float s = 0.f;
        for (int c = 0; c < C; ++c) s += W[k * OC + hh * C + c] * a_d[hh * C + c];
        v = s;
    }
    wt[(size_t)col * 128 + k] = f2bf(v);
}

// ==================== MFMA GEMM body: h = x @ Wext (K=128) ====================
template <int OC, int NT, bool AF32>
__device__ __forceinline__ void gemm_body(int gb, const void* __restrict__ xin,
                                          const ushort16* __restrict__ wt,
                                          ushort16* __restrict__ h, float4* __restrict__ att,
                                          float2* __restrict__ asc, int N) {
    const int wave = threadIdx.x >> 6, lane = threadIdx.x & 63;
    const int tile = gb * 4 + wave;
    if (tile * 16 >= N) return;
    const int m = lane & 15, quad = lane >> 4;
    const int node = tile * 16 + m;

    bf16x8 a[4];
    if (AF32) {
        const float* xr = (const float*)xin + (size_t)node * 128 + quad * 8;
#pragma unroll
        for (int c = 0; c < 4; ++c) {
            float4 u = *(const float4*)(xr + c * 32);
            float4 v = *(const float4*)(xr + c * 32 + 4);
            bf16x8 t;
            t[0] = (short)f2bf(u.x); t[1] = (short)f2bf(u.y);
            t[2] = (short)f2bf(u.z); t[3] = (short)f2bf(u.w);
            t[4] = (short)f2bf(v.x); t[5] = (short)f2bf(v.y);
            t[6] = (short)f2bf(v.z); t[7] = (short)f2bf(v.w);
            a[c] = t;
        }
    } else {
        const ushort16* xr = (const ushort16*)xin + (size_t)node * 128 + quad * 8;
#pragma unroll
        for (int c = 0; c < 4; ++c) a[c] = *(const bf16x8*)(xr + c * 32);
    }

    for (int t = 0; t < NT; ++t) {
        const ushort16* wr = wt + ((size_t)(t * 16 + m)) * 128 + quad * 8;
        bf16x8 b[4];
#pragma unroll
        for (int c = 0; c < 4; ++c) b[c] = *(const bf16x8*)(wr + c * 32);
        f32x4 acc = {0.f, 0.f, 0.f, 0.f};
#pragma unroll
        for (int c = 0; c < 4; ++c)
            acc = __builtin_amdgcn_mfma_f32_16x16x32_bf16(a[c], b[c], acc, 0, 0, 0);
        if (t * 16 < OC) {
#pragma unroll
            for (int r = 0; r < 4; ++r) {
                int nrow = tile * 16 + quad * 4 + r;
                h[(size_t)nrow * OC + t * 16 + m] = f2bf(acc[r]);
            }
        } else if (m < 4) {
#pragma unroll
            for (int r = 0; r < 4; ++r) {
                int nrow = tile * 16 + quad * 4 + r;
                ((float*)(att + nrow))[m] = acc[r];
                if (m < 2) ((float*)(asc + nrow))[m] = acc[r];
            }
        }
    }
}

// == K1: fused independent prep (hist | pack W1 | pack W2 | BN fold | graph bounds) ==
__global__ __launch_bounds__(256) void fused_prep(
    const int* __restrict__ ei, int E, int Etot, int nbuck, int chunk, int* __restrict__ hist,
    const float* __restrict__ W1, const float* __restrict__ as1, const float* __restrict__ ad1,
    ushort16* __restrict__ wt1,
    const float* __restrict__ W2, const float* __restrict__ as2, const float* __restrict__ ad2,
    ushort16* __restrict__ wt2,
    const float* __restrict__ b1, const float* __restrict__ g1, const float* __restrict__ be1,
    const float* __restrict__ mu1, const float* __restrict__ vr1,
    const float* __restrict__ b2, const float* __restrict__ g2, const float* __restrict__ be2,
    const float* __restrict__ mu2, const float* __restrict__ vr2,
    float2* __restrict__ bn1, float2* __restrict__ bn2,
    const int* __restrict__ batch, int N, int G, int* __restrict__ gstart) {
    const int bid = blockIdx.x;
    if (bid < P_PART) {
        // ---- role: per-partition bucket histogram ----
        __shared__ int lh[MAXB];
        const int p = bid;
        for (int i = threadIdx.x; i < nbuck; i += 256) lh[i] = 0;
        __syncthreads();
        const int beg = p * chunk;
        const int end = min(beg + chunk, Etot);
        for (int i = beg + threadIdx.x; i < end; i += 256) {
            int d = (i < E) ? ei[E + i] : i - E;
            atomicAdd(&lh[d >> BSHIFT], 1);
        }
        __syncthreads();
        for (int i = threadIdx.x; i < nbuck; i += 256) hist[(size_t)i * P_PART + p] = lh[i];
        return;
    }
    int rb = bid - P_PART;
    if (rb < 72) {
        // ---- role: pack W1 (144 cols, 2 per block) ----
        pack_col<128, 64>(rb * 2 + (threadIdx.x >> 7), threadIdx.x & 127, W1, as1, ad1, wt1);
        return;
    }
    rb -= 72;
    if (rb < 40) {
        // ---- role: pack W2 (80 cols, 2 per block) ----
        pack_col<64, 32>(rb * 2 + (threadIdx.x >> 7), threadIdx.x & 127, W2, as2, ad2, wt2);
        return;
    }
    rb -= 40;
    if (rb == 0) {
        // ---- role: fold BN params into per-channel (A, C): out = A*val + C ----
        const int c = threadIdx.x;
        if (c < 128) {
            float A = g1[c] * rsqrtf(vr1[c] + BN_EPS);
            bn1[c] = make_float2(A, A * (b1[c] - mu1[c]) + be1[c]);
        } else if (c < 160) {
            const int c2 = c - 128;
            float A = g2[c2] * rsqrtf(vr2[c2] + BN_EPS);
            bn2[c2] = make_float2(A, A * (b2[c2] - mu2[c2]) + be2[c2]);
        }
        return;
    }
    rb -= 1;
    {
        // ---- role: graph bounds (binary search; batch sorted) ----
        int g = rb * 256 + (int)threadIdx.x;
        if (g > G) return;
        if (g == G) { gstart[G] = N; return; }
        int lo = 0, hi = N;
        while (lo < hi) { int mid = (lo + hi) >> 1; if (batch[mid] < g) lo = mid + 1; else hi = mid; }
        gstart[g] = lo;
    }
}

// ---- K2: per-bucket exclusive scan over its 256 partition counts (block per bucket) ----
__global__ __launch_bounds__(P_PART) void row_scan(int* __restrict__ hist,
                                                   int* __restrict__ rowtot) {
    const int b = blockIdx.x;
    __shared__ int s[P_PART];
    const int t = threadIdx.x;
    int v = hist[(size_t)b * P_PART + t];
    s[t] = v;
    __syncthreads();
    for (int off = 1; off < P_PART; off <<= 1) {
        int u = (t >= off) ? s[t - off] : 0;
        __syncthreads();
        s[t] += u;
        __syncthreads();
    }
    hist[(size_t)b * P_PART + t] = s[t] - v;  // exclusive within bucket
    if (t == P_PART - 1) rowtot[b] = s[t];
}

// ====== K3: fused (rank_scatter | gemm1) — gemm1 has no dependency on the CSR chain ======
__global__ __launch_bounds__(256) void fused_scatter_gemm1(
    const int* __restrict__ ei, int E, int Etot, int nbuck, int chunk,
    const int* __restrict__ hist, const int* __restrict__ rowtot, uint32* __restrict__ ebuf,
    const void* __restrict__ x, const ushort16* __restrict__ wt1,
    ushort16* __restrict__ h1, float4* __restrict__ att1, float2* __restrict__ asc1, int N) {
    const int bid = blockIdx.x;
    if (bid < P_PART) {
        // ---- role: rank scatter (LDS cursors over disjoint (b,p) ranges) ----
        __shared__ int sb[MAXB + 1];
        __shared__ int cur[MAXB];
        scan_bbase(rowtot, nbuck, Etot, sb);
        const int p = bid;
        for (int i = threadIdx.x; i < nbuck; i += 256)
            cur[i] = sb[i] + hist[(size_t)i * P_PART + p];
        __syncthreads();
        const int beg = p * chunk;
        const int end = min(beg + chunk, Etot);
        for (int i = beg + threadIdx.x; i < end; i += 256) {
            int s_, d_;
            if (i < E) { s_ = ei[i]; d_ = ei[E + i]; }
            else       { s_ = d_ = i - E; }
            int pos = atomicAdd(&cur[d_ >> BSHIFT], 1);
            ebuf[pos] = ((uint32)(d_ & ((1 << BSHIFT) - 1)) << 25) | (uint32)s_;
        }
    } else {
        // ---- role: layer-1 GEMM ----
        gemm_body<128, 9, true>(bid - P_PART, x, wt1, h1, att1, asc1, N);
    }
}

// ---- K4: block per bucket — node-degree histogram + scan -> base[], place edges ----
__global__ __launch_bounds__(256) void bucket_place(
    const int* __restrict__ rowtot, int nbuck, int Etot, const uint32* __restrict__ ebuf,
    int N, int* __restrict__ base, int* __restrict__ csr_src) {
    const int bk = blockIdx.x;
    __shared__ int sb[MAXB + 1];
    __shared__ int ldeg[1 << BSHIFT];
    __shared__ int sscan[1 << BSHIFT];
    __shared__ int lcur[1 << BSHIFT];
    scan_bbase(rowtot, nbuck, Etot, sb);
    const int t = threadIdx.x;
    if (t < (1 << BSHIFT)) { ldeg[t] = 0; lcur[t] = 0; }
    __syncthreads();
    const int beg = sb[bk], end = sb[bk + 1];
    for (int i = beg + t; i < end; i += 256) atomicAdd(&ldeg[ebuf[i] >> 25], 1);
    __syncthreads();
    if (t < 128) sscan[t] = ldeg[t];
    __syncthreads();
    for (int off = 1; off < 128; off <<= 1) {
        int v = 0;
        if (t < 128 && t >= off) v = sscan[t - off];
        __syncthreads();
        if (t < 128) sscan[t] += v;
        __syncthreads();
    }
    if (t < 128) {
        int node = (bk << BSHIFT) + t;
        if (node < N) base[node] = beg + sscan[t] - ldeg[t];
    }
    __syncthreads();
    for (int i = beg + t; i < end; i += 256) {
        uint32 pk = ebuf[i];
        int dl = (int)(pk >> 25);
        int s_ = (int)(pk & 0x1FFFFFFu);
        int pos = beg + (sscan[dl] - ldeg[dl]) + atomicAdd(&lcur[dl], 1);
        csr_src[pos] = s_;
    }
}

// ========== K5: layer-1 gather + BN + ReLU + FUSED layer-2 GEMM ==========
// Gather phase latency-pipelined (R5). Epilogue writes the block's 16x128 bf16
// tile to LDS (row stride 272B -> <=2-way bank aliasing); after one barrier the
// 4 waves run the 16x80 MFMA against wt2 and emit h2/att2/asc2 directly.
__global__ __launch_bounds__(256) void gat_gather1(
    const int* __restrict__ base, const int* __restrict__ csr_src, int Etot, int N,
    const ushort16* __restrict__ h, const float4* __restrict__ att,
    const float2* __restrict__ asc, const float2* __restrict__ bn1,
    const ushort16* __restrict__ wt2, ushort16* __restrict__ h2,
    float4* __restrict__ att2, float2* __restrict__ asc2) {
    __shared__ char agg_lds[16 * 272];
    const int tid = threadIdx.x;
    const int nr = tid >> 4;                    // node row in tile (0..15)
    const int node = blockIdx.x * 16 + nr;
    const bool live = node < N;
    const int t = tid & 63;        // lane in wave
    const int q = tid & 15;        // lane in group: channels 8q..8q+7
    const int gbase = t & 48;      // group's first lane (within wave)
    const int hh = q >> 3;         // head
    const int hbit = q & 8;        // head bit for ex-shuffle lane
    const int eh = q & 7;          // edge slot this lane evaluates in phase 1
    int beg = 0, deg = 0;
    float ad = 0.f;
    if (live) {
        beg = base[node];
        const int end = (node + 1 < N) ? base[node + 1] : Etot;
        deg = end - beg;           // >= 1 (self loop)
        const float4 adn = att[node];
        ad = hh ? adn.w : adn.z;
    }
    const char* hq = (const char*)h + q * 16;   // this lane's 16B slice of each row

    f32x2 ac0 = {0.f, 0.f}, ac1 = {0.f, 0.f}, ac2 = {0.f, 0.f}, ac3 = {0.f, 0.f};
    float ssum = 0.f;

    // prefetch chunk 0's source index (clamped to slot 0 for invalid lanes)
    int sidxme = csr_src[beg + ((eh < deg) ? eh : 0)];

    for (int c0e = 0; c0e < deg; c0e += 8) {
        const int degc = min(deg - c0e, 8);
        const bool ok = eh < degc;
        const int offme = sidxme << 8;          // 256B rows
        const float av = ((const float*)asc)[2 * sidxme + hh];
        uint4 hv[8];
#pragma unroll
        for (int s = 0; s < 8; ++s) {
            const int ofs = __shfl(offme, gbase + s, 64);
            hv[s] = *(const uint4*)(hq + ofs);
        }
        const int nb = c0e + 8;
        const int na = (nb < deg) ? (nb + ((eh < deg - nb) ? eh : 0)) : 0;
        const int sidx_next = csr_src[beg + na];
        float e = av + ad;
        e = e > 0.f ? e : NEG_SLOPE * e;
        const float x = ok ? __expf(e) : 0.f;
        float r = x;
#pragma unroll
        for (int off = 1; off < 8; off <<= 1) r += __shfl_xor(r, off, 64);
        ssum += r;
#pragma unroll
        for (int e0 = 0; e0 < 8; e0 += 4) {
            if (e0 < degc) {
#pragma unroll
                for (int j = 0; j < 4; ++j) {
                    const float ex = __shfl(x, (gbase + e0 + j) | hbit, 64);
                    f32x2 ex2; ex2.x = ex; ex2.y = ex;
                    ac0 = pkfma(ex2, hv[e0 + j].x, ac0);
                    ac1 = pkfma(ex2, hv[e0 + j].y, ac1);
                    ac2 = pkfma(ex2, hv[e0 + j].z, ac2);
                    ac3 = pkfma(ex2, hv[e0 + j].w, ac3);
                }
            }
        }
        sidxme = sidx_next;
    }
    // ---- epilogue: folded BN + ReLU -> LDS tile (bf16) ----
    const float inv = 1.f / (ssum + 1e-16f);
    const int c0 = 8 * q;
    const float4* bp = (const float4*)(bn1 + c0);  // (A,C) pairs, channels c0..c0+7
    const float4 w0 = bp[0], w1 = bp[1], w2 = bp[2], w3 = bp[3];
    float va[8] = {ac0.x, ac0.y, ac1.x, ac1.y, ac2.x, ac2.y, ac3.x, ac3.y};
    float Ac[8] = {w0.x, w0.z, w1.x, w1.z, w2.x, w2.z, w3.x, w3.z};
    float Cc[8] = {w0.y, w0.w, w1.y, w1.w, w2.y, w2.w, w3.y, w3.w};
    uint32 pk[4];
#pragma unroll
    for (int i = 0; i < 8; i += 2) {
        float v0 = fmaxf(fmaf(Ac[i], va[i] * inv, Cc[i]), 0.f);
        float v1 = fmaxf(fmaf(Ac[i + 1], va[i + 1] * inv, Cc[i + 1]), 0.f);
        pk[i >> 1] = (uint32)f2bf(v0) | ((uint32)f2bf(v1) << 16);
    }
    *(uint4*)(agg_lds + nr * 272 + q * 16) = make_uint4(pk[0], pk[1], pk[2], pk[3]);
    __syncthreads();

    // ---- fused layer-2 GEMM: 16x128 (LDS) x 128x80 (wt2) ----
    const int wave = tid >> 6;
    const int m = t & 15, quad = t >> 4;
    bf16x8 a[4];
#pragma unroll
    for (int c = 0; c < 4; ++c)
        a[c] = *(const bf16x8*)(agg_lds + m * 272 + quad * 16 + c * 64);
    const int tile0 = blockIdx.x * 16;
#pragma unroll
    for (int tt = 0; tt < 2; ++tt) {
        const int tcol = wave + tt * 4;          // wave0: tiles 0,4; waves1-3: tiles 1-3
        if (tcol < 5) {
            const ushort16* wr = wt2 + ((size_t)(tcol * 16 + m)) * 128 + quad * 8;
            bf16x8 b[4];
#pragma unroll
            for (int c = 0; c < 4; ++c) b[c] = *(const bf16x8*)(wr + c * 32);
            f32x4 acc = {0.f, 0.f, 0.f, 0.f};
#pragma unroll
            for (int c = 0; c < 4; ++c)
                acc = __builtin_amdgcn_mfma_f32_16x16x32_bf16(a[c], b[c], acc, 0, 0, 0);
            if (tcol * 16 < 64) {
#pragma unroll
                for (int r = 0; r < 4; ++r) {
                    int nrow = tile0 + quad * 4 + r;
                    if (nrow < N) h2[(size_t)nrow * 64 + tcol * 16 + m] = f2bf(acc[r]);
                }
            } else if (m < 4) {
#pragma unroll
                for (int r = 0; r < 4; ++r) {
                    int nrow = tile0 + quad * 4 + r;
                    if (nrow < N) {
                        ((float*)(att2 + nrow))[m] = acc[r];
                        if (m < 2) ((float*)(asc2 + nrow))[m] = acc[r];
                    }
                }
            }
        }
    }
}

// ====== K6: layer-2 gather + head-mean + folded BN -> node_out (coalesced) ======
__global__ __launch_bounds__(256) void gat_gather2(
    const int* __restrict__ base, const int* __restrict__ csr_src, int Etot, int N,
    const ushort16* __restrict__ h2, const float4* __restrict__ att,
    const float2* __restrict__ asc, const float2* __restrict__ bn2,
    float* __restrict__ node_out) {
    const int tid = threadIdx.x;
    const int node = blockIdx.x * 16 + (tid >> 4);
    if (node >= N) return;
    const int t = tid & 63;
    const int q = tid & 15;        // channels 4q..4q+3
    const int gbase = t & 48;
    const int hh = q >> 3;
    const int hbit = q & 8;
    const int eh = q & 7;
    const int beg = base[node];
    const int end = (node + 1 < N) ? base[node + 1] : Etot;
    const int deg = end - beg;
    const float4 adn = att[node];
    const float ad = hh ? adn.w : adn.z;
    const char* hq = (const char*)h2 + q * 8;   // this lane's 8B slice of each row

    f32x2 ac0 = {0.f, 0.f}, ac1 = {0.f, 0.f};
    float ssum = 0.f;

    int sidxme = csr_src[beg + ((eh < deg) ? eh : 0)];

    for (int c0e = 0; c0e < deg; c0e += 8) {
        const int degc = min(deg - c0e, 8);
        const bool ok = eh < degc;
        const int offme = sidxme << 7;          // 128B rows
        const float av = ((const float*)asc)[2 * sidxme + hh];
        uint2 hv[8];
#pragma unroll
        for (int s = 0; s < 8; ++s) {
            const int ofs = __shfl(offme, gbase + s, 64);
            hv[s] = *(const uint2*)(hq + ofs);
        }
        const int nb = c0e + 8;
        const int na = (nb < deg) ? (nb + ((eh < deg - nb) ? eh : 0)) : 0;
        const int sidx_next = csr_src[beg + na];
        float e = av + ad;
        e = e > 0.f ? e : NEG_SLOPE * e;
        const float x = ok ? __expf(e) : 0.f;
        float r = x;
#pragma unroll
        for (int off = 1; off < 8; off <<= 1) r += __shfl_xor(r, off, 64);
        ssum += r;
#pragma unroll
        for (int e0 = 0; e0 < 8; e0 += 4) {
            if (e0 < degc) {
#pragma unroll
                for (int j = 0; j < 4; ++j) {
                    const float ex = __shfl(x, (gbase + e0 + j) | hbit, 64);
                    f32x2 ex2; ex2.x = ex; ex2.y = ex;
                    ac0 = pkfma(ex2, hv[e0 + j].x, ac0);
                    ac1 = pkfma(ex2, hv[e0 + j].y, ac1);
                }
            }
        }
        sidxme = sidx_next;
    }
    const float inv = 1.f / (ssum + 1e-16f);
    float v0 = ac0.x * inv, v1 = ac0.y * inv, v2 = ac1.x * inv, v3 = ac1.y * inv;
    // head mean: lane q<8 (head0 ch 4q..4q+3) pairs with lane q+8 (head1 ch 32+4q..)
    const int psrc = gbase | ((q + 8) & 15);
    float p0 = __shfl(v0, psrc, 64);
    float p1 = __shfl(v1, psrc, 64);
    float p2 = __shfl(v2, psrc, 64);
    float p3 = __shfl(v3, psrc, 64);
    if (q < 8) {
        const int c0 = 4 * q;
        const float4* bp = (const float4*)(bn2 + c0);  // (A,C) pairs, channels c0..c0+3
        const float4 w0 = bp[0], w1 = bp[1];
        float m0 = fmaf(w0.x, 0.5f * (v0 + p0), w0.y);
        float m1 = fmaf(w0.z, 0.5f * (v1 + p1), w0.w);
        float m2 = fmaf(w1.x, 0.5f * (v2 + p2), w1.y);
        float m3 = fmaf(w1.z, 0.5f * (v3 + p3), w1.w);
        *(float4*)(node_out + (size_t)node * 32 + c0) = make_float4(m0, m1, m2, m3);
    }
}

// ============ K7: block-per-graph mean over nodes + log_softmax (32 classes) ============
__global__ __launch_bounds__(256) void pool_logsoftmax(
    const float* __restrict__ node_out, const int* __restrict__ gstart,
    float* __restrict__ out) {
    const int gidx = blockIdx.x;
    const int tid = threadIdx.x;
    const int c = tid & 31, r = tid >> 5;
    const int n0 = gstart[gidx], n1 = gstart[gidx + 1];
    float s = 0.f;
    for (int n = n0 + r; n < n1; n += 8) s += node_out[(size_t)n * 32 + c];
    __shared__ float red[8][32];
    red[r][c] = s;
    __syncthreads();
    if (r == 0) {
        float tot = red[0][c];
#pragma unroll
        for (int k = 1; k < 8; ++k) tot += red[k][c];
        float v = tot / fmaxf((float)(n1 - n0), 1.f);
        float m = v;
#pragma unroll
        for (int off = 16; off >= 1; off >>= 1) m = fmaxf(m, __shfl_xor(m, off, 64));
        float ex = __expf(v - m);
        float ssum = ex;
#pragma unroll
        for (int off = 16; off >= 1; off >>= 1) ssum += __shfl_xor(ssum, off, 64);
        out[gidx * 32 + c] = v - m - logf(ssum);
    }
}

extern "C" void kernel_launch(void* const* d_in, const int* in_sizes, int n_in,
                              void* d_out, int out_size, void* d_ws, size_t ws_size,
                              hipStream_t stream) {
    const float* x   = (const float*)d_in[0];
    const int* ei    = (const int*)d_in[1];
    const int* batch = (const int*)d_in[2];
    const float* W1  = (const float*)d_in[3];
    const float* as1 = (const float*)d_in[4];
    const float* ad1 = (const float*)d_in[5];
    const float* b1  = (const float*)d_in[6];
    const float* g1  = (const float*)d_in[7];
    const float* be1 = (const float*)d_in[8];
    const float* mu1 = (const float*)d_in[9];
    const float* vr1 = (const float*)d_in[10];
    const float* W2  = (const float*)d_in[11];
    const float* as2 = (const float*)d_in[12];
    const float* ad2 = (const float*)d_in[13];
    const float* b2  = (const float*)d_in[14];
    const float* g2  = (const float*)d_in[15];
    const float* be2 = (const float*)d_in[16];
    const float* mu2 = (const float*)d_in[17];
    const float* vr2 = (const float*)d_in[18];
    float* out = (float*)d_out;

    const int N = in_sizes[0] / 128;
    const int E = in_sizes[1] / 2;
    const int Etot = E + N;
    const int G = out_size / 32;
    const int nbuck = (N + (1 << BSHIFT) - 1) >> BSHIFT;
    const int chunk = (Etot + P_PART - 1) / P_PART;
    const int M = nbuck * P_PART;
    const int ntile = (N + 15) / 16;
    const int gemm_grid = (ntile + 3) / 4;
    const int gbb = (G + 1 + 255) / 256;  // graph_bounds blocks (g in [0, G])

    // ---- workspace layout (units: floats; keep every region 16B-aligned) ----
    float* p = (float*)d_ws;
    size_t o = 0;
    auto al = [&]() { o = (o + 3) & ~(size_t)3; };
    ushort16* h1b   = (ushort16*)(p + o); o += (size_t)N * 64;  al();  // N*128 bf16
    ushort16* h2b   = (ushort16*)(p + o); o += (size_t)N * 32;  al();  // N*64 bf16
    float4* att1 = (float4*)(p + o); o += (size_t)N * 4;  al();
    float4* att2 = (float4*)(p + o); o += (size_t)N * 4;  al();
    float2* asc1 = (float2*)(p + o); o += (size_t)N * 2;  al();
    float2* asc2 = (float2*)(p + o); o += (size_t)N * 2;  al();
    float* nodeo = p + o; o += (size_t)N * 32; al();
    ushort16* wt1 = (ushort16*)(p + o); o += (size_t)144 * 64; al();   // 144x128 bf16
    ushort16* wt2 = (ushort16*)(p + o); o += (size_t)80 * 64;  al();   // 80x128 bf16
    float2* bn1  = (float2*)(p + o); o += (size_t)128 * 2; al();
    float2* bn2  = (float2*)(p + o); o += (size_t)32 * 2;  al();
    int* csr_src = (int*)(p + o); o += (size_t)Etot; al();
    uint32* ebuf = (uint32*)(p + o); o += (size_t)Etot; al();
    int* base    = (int*)(p + o); o += (size_t)N;    al();
    int* hist    = (int*)(p + o); o += (size_t)M;    al();
    int* rowtot  = (int*)(p + o); o += (size_t)nbuck + 4; al();
    int* gstart  = (int*)(p + o); o += (size_t)G + 4; al();
    // (no zero-init needed: every buffer is fully written before it is read)

    // K1: hist | pack W1 | pack W2 | BN fold | graph bounds (all independent)
    fused_prep<<<P_PART + 72 + 40 + 1 + gbb, 256, 0, stream>>>(
        ei, E, Etot, nbuck, chunk, hist, W1, as1, ad1, wt1, W2, as2, ad2, wt2,
        b1, g1, be1, mu1, vr1, b2, g2, be2, mu2, vr2, bn1, bn2,
        batch, N, G, gstart);
    // K2: per-bucket scan of partition counts
    row_scan<<<nbuck, P_PART, 0, stream>>>(hist, rowtot);
    // K3: rank scatter | layer-1 GEMM (independent; overlap in one launch)
    fused_scatter_gemm1<<<P_PART + gemm_grid, 256, 0, stream>>>(
        ei, E, Etot, nbuck, chunk, hist, rowtot, ebuf, x, wt1, h1b, att1, asc1, N);
    // K4: per-bucket placement -> CSR
    bucket_place<<<nbuck, 256, 0, stream>>>(rowtot, nbuck, Etot, ebuf, N, base, csr_src);
    // K5: layer-1 gather + BN + ReLU + fused layer-2 GEMM (16 nodes per block)
    gat_gather1<<<ntile, 256, 0, stream>>>(base, csr_src, Etot, N, h1b, att1, asc1,
                                           bn1, wt2, h2b, att2, asc2);
    // K6: layer-2 gather + head-mean + BN -> node_out
    gat_gather2<<<ntile, 256, 0, stream>>>(base, csr_src, Etot, N, h2b, att2, asc2,
                                           bn2, nodeo);
    // K7: per-graph mean + log_softmax
    pool_logsoftmax<<<G, 256, 0, stream>>>(nodeo, gstart, out);
}